// Round 1
// baseline (692.406 us; speedup 1.0000x reference)
//
#include <hip/hip_runtime.h>
#include <math.h>

// Problem constants
#define NB      32
#define DDIM    256
#define HWSZ    1024                 // H*W
#define NTOK    32768                // NB*HWSZ
#define KCB     1024                 // codebook size
#define BSTRIDE (DDIM*HWSZ)          // 262144 floats per batch image

// ws layout (bytes). Total needed: 664576 (~650 KB).
#define OFF_ESQ   0          // 1024 f32
#define OFF_ZESQ  4096       // 32768 f32
#define OFF_CNT   135168     // 1024 u32
#define OFF_PART  139264     // 128 double
#define OFF_PM    140288     // 2*32768 u64 (per-K-half packed argmin)

// ---------------------------------------------------------------- init
__global__ __launch_bounds__(256) void k_init(unsigned* counts) {
    int t = blockIdx.x * 256 + threadIdx.x;
    if (t < KCB) counts[t] = 0u;
}

// ---------------------------------------------------------------- e_sq[k]
__global__ __launch_bounds__(256) void k_esq(const float* __restrict__ E,
                                             float* __restrict__ esq) {
    int wave = threadIdx.x >> 6, lane = threadIdx.x & 63;
    int c = blockIdx.x * 4 + wave;                 // grid 256 -> 1024 codes
    const float4 v = *reinterpret_cast<const float4*>(&E[(size_t)c * DDIM + lane * 4]);
    double s = (double)v.x * v.x + (double)v.y * v.y +
               (double)v.z * v.z + (double)v.w * v.w;
    for (int off = 32; off; off >>= 1) s += __shfl_down(s, off, 64);
    if (lane == 0) esq[c] = (float)s;
}

// ---------------------------------------------------------------- ze_sq[n]
__global__ __launch_bounds__(256) void k_zesq(const float* __restrict__ in,
                                              float* __restrict__ zesq) {
    int n = blockIdx.x * 256 + threadIdx.x;        // grid 128
    int b = n >> 10, hw = n & 1023;
    const float* p = in + (size_t)b * BSTRIDE + hw;
    double s = 0.0;
#pragma unroll 8
    for (int d = 0; d < DDIM; ++d) { float v = p[(size_t)d * HWSZ]; s += (double)v * v; }
    zesq[n] = (float)s;
}

// ---------------------------------------------------------------- GEMM + argmin
// grid 512 = (256 token tiles of 128) x (2 K-halves of 512 codes)
// block 256 = 16(tx: codes) x 16(ty: tokens); thread tile 8 tok x 8 codes
union GemmLds {
    struct { float zs[64][128]; float es[64][128]; } s;   // 65536 B exactly
    unsigned long long red[128][16];                      // overlay (16 KB)
};

__global__ __launch_bounds__(256, 2) void k_gemm(const float* __restrict__ in,
                                                 const float* __restrict__ E,
                                                 const float* __restrict__ zesq,
                                                 const float* __restrict__ esq,
                                                 unsigned long long* __restrict__ pm) {
    __shared__ GemmLds lds;
    const int t  = threadIdx.x;
    const int tx = t & 15, ty = t >> 4;
    const int tile = blockIdx.x >> 1, half = blockIdx.x & 1;
    const int n0 = tile * 128;
    const int b = n0 >> 10, hw0 = n0 & 1023;       // 128 tokens stay in one b
    const float* inb = in + (size_t)b * BSTRIDE + hw0;

    float zesq_r[8];
#pragma unroll
    for (int m = 0; m < 8; ++m) zesq_r[m] = zesq[n0 + ty * 8 + m];

    float minv[8]; int mini[8];
#pragma unroll
    for (int m = 0; m < 8; ++m) { minv[m] = HUGE_VALF; mini[m] = 0; }

    for (int kb = 0; kb < 4; ++kb) {
        const int kbase = half * 512 + kb * 128;
        float esq_r[8];
#pragma unroll
        for (int n = 0; n < 8; ++n) esq_r[n] = esq[kbase + tx * 8 + n];

        float acc[8][8];
#pragma unroll
        for (int m = 0; m < 8; ++m)
#pragma unroll
            for (int n = 0; n < 8; ++n) acc[m][n] = 0.f;

        for (int db = 0; db < 4; ++db) {
            __syncthreads();
            // stage Ze chunk: [64 d][128 tok], coalesced global, conflict-free LDS
#pragma unroll
            for (int r = 0; r < 32; ++r) {
                int idx = r * 256 + t;
                int i = idx & 127, dj = idx >> 7;
                lds.s.zs[dj][i] = inb[(size_t)(db * 64 + dj) * HWSZ + i];
            }
            // stage E chunk: [64 d][128 codes], XOR-swizzled at float4 granularity
#pragma unroll
            for (int r = 0; r < 32; ++r) {
                int idx = r * 256 + t;
                int dd = idx & 63, cc = idx >> 6;
                int col = (cc & 3) + 4 * ((cc >> 2) ^ (dd & 7));
                lds.s.es[dd][col] = E[(size_t)(kbase + cc) * DDIM + db * 64 + dd];
            }
            __syncthreads();
#pragma unroll 2
            for (int dd = 0; dd < 64; ++dd) {
                const float4 z0 = *reinterpret_cast<const float4*>(&lds.s.zs[dd][ty * 8]);
                const float4 z1 = *reinterpret_cast<const float4*>(&lds.s.zs[dd][ty * 8 + 4]);
                int q0 = (tx * 2) ^ (dd & 7);
                const float4 e0 = *reinterpret_cast<const float4*>(&lds.s.es[dd][q0 * 4]);
                const float4 e1 = *reinterpret_cast<const float4*>(&lds.s.es[dd][(q0 ^ 1) * 4]);
                float zz[8] = {z0.x, z0.y, z0.z, z0.w, z1.x, z1.y, z1.z, z1.w};
                float ee[8] = {e0.x, e0.y, e0.z, e0.w, e1.x, e1.y, e1.z, e1.w};
#pragma unroll
                for (int m = 0; m < 8; ++m)
#pragma unroll
                    for (int n = 0; n < 8; ++n)
                        acc[m][n] = fmaf(zz[m], ee[n], acc[m][n]);
            }
        }
        // running argmin update, mirroring ref fp32 rounding:
        // dist = fl( fl(ze_sq + e_sq) - fl(2*dot) ), unfused.
#pragma unroll
        for (int m = 0; m < 8; ++m) {
#pragma unroll
            for (int n = 0; n < 8; ++n) {
                float t1 = __fadd_rn(zesq_r[m], esq_r[n]);
                float s  = __fsub_rn(t1, __fmul_rn(2.0f, acc[m][n]));
                if (s < minv[m]) { minv[m] = s; mini[m] = kbase + tx * 8 + n; }
            }
        }
    }

    // cross-thread reduce per token; key = ordered(val)<<32 | idx
    __syncthreads();
#pragma unroll
    for (int m = 0; m < 8; ++m) {
        unsigned uo = __float_as_uint(minv[m]);
        uo = (uo & 0x80000000u) ? ~uo : (uo | 0x80000000u);
        lds.red[ty * 8 + m][tx] = ((unsigned long long)uo << 32) | (unsigned)mini[m];
    }
    __syncthreads();
    if (t < 128) {
        unsigned long long kmin = lds.red[t][0];
#pragma unroll
        for (int j = 1; j < 16; ++j) {
            unsigned long long v = lds.red[t][j];
            if (v < kmin) kmin = v;
        }
        pm[(size_t)half * NTOK + n0 + t] = kmin;
    }
}

// ---------------------------------------------------------------- epilogue
__global__ __launch_bounds__(256) void k_epi(const float* __restrict__ in,
                                             const float* __restrict__ E,
                                             const unsigned long long* __restrict__ pm,
                                             unsigned* __restrict__ counts,
                                             double* __restrict__ partials,
                                             float* __restrict__ out) {
    int n = blockIdx.x * 256 + threadIdx.x;        // grid 128
    unsigned long long k0 = pm[n], k1 = pm[NTOK + n];
    unsigned long long km = (k1 < k0) ? k1 : k0;   // ties -> half 0 (smaller idx)
    int idx = (int)(km & 0xffffffffull);
    atomicAdd(&counts[idx], 1u);

    int b = n >> 10, hw = n & 1023;
    const float* zp = in + (size_t)b * BSTRIDE + hw;
    float*       op = out + 1 + (size_t)b * BSTRIDE + hw;   // out[0] = loss
    const float* ep = E + (size_t)idx * DDIM;

    double s = 0.0;
#pragma unroll 4
    for (int d = 0; d < DDIM; ++d) {
        float ze = zp[(size_t)d * HWSZ];
        float zq = ep[d];
        float df = __fsub_rn(zq, ze);              // fl(zq - ze)
        float ov = __fadd_rn(ze, df);              // fl(ze + fl(zq - ze))
        op[(size_t)d * HWSZ] = ov;
        float sq = __fmul_rn(df, df);
        s += (double)sq;
    }
    __shared__ double sd[256];
    sd[threadIdx.x] = s; __syncthreads();
    for (int off = 128; off; off >>= 1) {
        if (threadIdx.x < off) sd[threadIdx.x] += sd[threadIdx.x + off];
        __syncthreads();
    }
    if (threadIdx.x == 0) partials[blockIdx.x] = sd[0];
}

// ---------------------------------------------------------------- finalize
__global__ __launch_bounds__(256) void k_final(const double* __restrict__ partials,
                                               const unsigned* __restrict__ counts,
                                               float* __restrict__ out) {
    __shared__ double sd[256];
    int t = threadIdx.x;
    double s = (t < 128) ? partials[t] : 0.0;
    sd[t] = s; __syncthreads();
    for (int off = 128; off; off >>= 1) {
        if (t < off) sd[t] += sd[t + off];
        __syncthreads();
    }
    double msum = sd[0];
    __syncthreads();

    double es_ = 0.0;
#pragma unroll
    for (int j = 0; j < 4; ++j) {
        unsigned c = counts[t * 4 + j];
        float p = (float)c / 32768.0f;             // exact (div by 2^15)
        float term = __fmul_rn(p, log2f(__fadd_rn(p, 1e-10f)));
        es_ += (double)term;
    }
    sd[t] = es_; __syncthreads();
    for (int off = 128; off; off >>= 1) {
        if (t < off) sd[t] += sd[t + off];
        __syncthreads();
    }
    if (t == 0) {
        float e = (float)(msum / 8388608.0);       // mean over B*D*H*W
        float q = e;                               // numerically identical in ref
        float loss = __fadd_rn(q, __fmul_rn(0.25f, e));
        float ent = -(float)sd[0];
        float words = exp2f(ent);
        out[0] = loss;
        out[1 + 8388608 + 0] = e;
        out[1 + 8388608 + 1] = q;
        out[1 + 8388608 + 2] = words;
    }
}

// ---------------------------------------------------------------- launch
extern "C" void kernel_launch(void* const* d_in, const int* in_sizes, int n_in,
                              void* d_out, int out_size, void* d_ws, size_t ws_size,
                              hipStream_t stream) {
    const float* in = (const float*)d_in[0];
    const float* E  = (const float*)d_in[1];
    float* out = (float*)d_out;
    char* ws = (char*)d_ws;
    float*              esq      = (float*)(ws + OFF_ESQ);
    float*              zesq     = (float*)(ws + OFF_ZESQ);
    unsigned*           counts   = (unsigned*)(ws + OFF_CNT);
    double*             partials = (double*)(ws + OFF_PART);
    unsigned long long* pm       = (unsigned long long*)(ws + OFF_PM);

    hipLaunchKernelGGL(k_init, dim3(4),   dim3(256), 0, stream, counts);
    hipLaunchKernelGGL(k_esq,  dim3(256), dim3(256), 0, stream, E, esq);
    hipLaunchKernelGGL(k_zesq, dim3(128), dim3(256), 0, stream, in, zesq);
    hipLaunchKernelGGL(k_gemm, dim3(512), dim3(256), 0, stream, in, E, zesq, esq, pm);
    hipLaunchKernelGGL(k_epi,  dim3(128), dim3(256), 0, stream, in, E, pm, counts, partials, out);
    hipLaunchKernelGGL(k_final, dim3(1),  dim3(256), 0, stream, partials, counts, out);
}

// Round 2
// 166.124 us; speedup vs baseline: 4.1680x; 4.1680x over previous
//
#include <hip/hip_runtime.h>
#include <hip/hip_bf16.h>
#include <math.h>

// Problem constants
#define NB      32
#define DDIM    256
#define HWSZ    1024                 // H*W
#define NTOK    32768                // NB*HWSZ
#define KCB     1024                 // codebook size
#define BSTRIDE (DDIM*HWSZ)          // floats per batch image

// ws layout (bytes); total ~797 KB
#define OFF_ESQ  0                   // 1024 f32
#define OFF_EBF  4096                // 1024*256 bf16 (512 KB)
#define OFF_CNT  528384              // 1024 u32
#define OFF_PART 532480              // 256 double
#define OFF_PM   534528              // 32768 u64

typedef __attribute__((ext_vector_type(8))) short s8v;   // 8 bf16 (4 VGPR)
typedef __attribute__((ext_vector_type(4))) float f4v;   // MFMA acc

__device__ inline unsigned short f2bf(float x) {
    __hip_bfloat16 h = __float2bfloat16(x);
    return __builtin_bit_cast(unsigned short, h);
}

// ---------------------------------------------------------------- init (runs every call)
__global__ __launch_bounds__(256) void k_init(unsigned long long* pm, unsigned* counts) {
    int t = blockIdx.x * 256 + threadIdx.x;          // grid 128 -> 32768
    pm[t] = ~0ull;
    if (t < KCB) counts[t] = 0u;
}

// ---------------------------------------------------------------- E -> bf16, esq
__global__ __launch_bounds__(256) void k_prep(const float* __restrict__ E,
                                              float* __restrict__ esq,
                                              unsigned short* __restrict__ Ebf) {
    int w = threadIdx.x >> 6, lane = threadIdx.x & 63;
    int code = blockIdx.x * 4 + w;                   // grid 256 -> 1024
    const float4 v = *reinterpret_cast<const float4*>(&E[(size_t)code * DDIM + lane * 4]);
    double s = (double)v.x * v.x + (double)v.y * v.y +
               (double)v.z * v.z + (double)v.w * v.w;
    for (int off = 32; off; off >>= 1) s += __shfl_down(s, off, 64);
    if (lane == 0) esq[code] = (float)s;
    ushort4 hv;
    hv.x = f2bf(v.x); hv.y = f2bf(v.y); hv.z = f2bf(v.z); hv.w = f2bf(v.w);
    *reinterpret_cast<ushort4*>(&Ebf[(size_t)code * DDIM + lane * 4]) = hv;
}

// ---------------------------------------------------------------- MFMA GEMM + argmin
// grid 2048 = 256 token-tiles(128) x 8 code-tiles(128); 256 thr = 4 waves (2x2)
// LDS tiles [128 rows][64 bf16], XOR-swizzled at 16B chunks: chunk' = chunk ^ (row&7)
__global__ __launch_bounds__(256) void k_gemm(const float* __restrict__ in,
                                              const unsigned short* __restrict__ Ebf,
                                              const float* __restrict__ esq,
                                              unsigned long long* __restrict__ pm) {
    __shared__ __align__(16) unsigned short As[128 * 64];   // 16 KB
    __shared__ __align__(16) unsigned short Bs[128 * 64];   // 16 KB

    const int t = threadIdx.x;
    const int bx = blockIdx.x >> 3;                  // token tile
    const int by = blockIdx.x & 7;                   // code tile
    const int n0 = bx * 128, c0 = by * 128;
    const int b = n0 >> 10, hw0 = n0 & 1023;         // 128 tokens stay in one b
    const float* inb = in + (size_t)b * BSTRIDE + hw0;

    const int lane = t & 63, w = t >> 6;
    const int wm = w >> 1, wn = w & 1;               // 2x2 wave grid (64x64 each)
    const int lrow = lane & 15, lk = lane >> 4;

    f4v acc[4][4];
#pragma unroll
    for (int mi = 0; mi < 4; ++mi)
#pragma unroll
        for (int ni = 0; ni < 4; ++ni) acc[mi][ni] = (f4v){0.f, 0.f, 0.f, 0.f};

    for (int kc = 0; kc < 4; ++kc) {                 // K chunks of 64
        __syncthreads();
        // --- stage A: [128 tok][64 d], fp32 NCHW -> bf16, reg transpose
#pragma unroll
        for (int i = 0; i < 4; ++i) {
            int W = i * 256 + t;
            int tok = (W & 63) + 64 * (W >> 9);
            int chunk = (W >> 6) & 7;
            int dbase = kc * 64 + chunk * 8;
            float v[8];
#pragma unroll
            for (int j = 0; j < 8; ++j) v[j] = inb[(size_t)(dbase + j) * HWSZ + tok];
            unsigned p0 = (unsigned)f2bf(v[0]) | ((unsigned)f2bf(v[1]) << 16);
            unsigned p1 = (unsigned)f2bf(v[2]) | ((unsigned)f2bf(v[3]) << 16);
            unsigned p2 = (unsigned)f2bf(v[4]) | ((unsigned)f2bf(v[5]) << 16);
            unsigned p3 = (unsigned)f2bf(v[6]) | ((unsigned)f2bf(v[7]) << 16);
            uint4 pk = {p0, p1, p2, p3};
            int cs = chunk ^ (tok & 7);
            *reinterpret_cast<uint4*>(&As[tok * 64 + cs * 8]) = pk;
        }
        // --- stage B: [128 code][64 d] from Ebf
#pragma unroll
        for (int i = 0; i < 4; ++i) {
            int W = i * 256 + t;
            int code = (W & 63) + 64 * (W >> 9);
            int chunk = (W >> 6) & 7;
            uint4 v = *reinterpret_cast<const uint4*>(
                &Ebf[(size_t)(c0 + code) * DDIM + kc * 64 + chunk * 8]);
            int cs = chunk ^ (code & 7);
            *reinterpret_cast<uint4*>(&Bs[code * 64 + cs * 8]) = v;
        }
        __syncthreads();
        // --- compute: 2 K-steps of 32
#pragma unroll
        for (int ks = 0; ks < 2; ++ks) {
            s8v a[4], bf[4];
#pragma unroll
            for (int mi = 0; mi < 4; ++mi) {
                int row = wm * 64 + mi * 16 + lrow;
                int cs = (ks * 4 + lk) ^ (row & 7);
                a[mi] = *reinterpret_cast<const s8v*>(&As[row * 64 + cs * 8]);
            }
#pragma unroll
            for (int ni = 0; ni < 4; ++ni) {
                int row = wn * 64 + ni * 16 + lrow;
                int cs = (ks * 4 + lk) ^ (row & 7);
                bf[ni] = *reinterpret_cast<const s8v*>(&Bs[row * 64 + cs * 8]);
            }
#pragma unroll
            for (int mi = 0; mi < 4; ++mi)
#pragma unroll
                for (int ni = 0; ni < 4; ++ni)
                    acc[mi][ni] = __builtin_amdgcn_mfma_f32_16x16x32_bf16(
                        a[mi], bf[ni], acc[mi][ni], 0, 0, 0);
        }
    }

    // --- argmin epilogue. dist' = esq[c] - 2*dot  (||z||^2 dropped: constant per row)
    float es_r[4];
#pragma unroll
    for (int ni = 0; ni < 4; ++ni) es_r[ni] = esq[c0 + wn * 64 + ni * 16 + lrow];

#pragma unroll
    for (int mi = 0; mi < 4; ++mi) {
#pragma unroll
        for (int r = 0; r < 4; ++r) {
            float best = HUGE_VALF; int bc = 0;
#pragma unroll
            for (int ni = 0; ni < 4; ++ni) {
                float d = fmaf(-2.0f, acc[mi][ni][r], es_r[ni]);
                if (d < best) { best = d; bc = c0 + wn * 64 + ni * 16 + lrow; }
            }
            unsigned u = __float_as_uint(best);
            u = (u & 0x80000000u) ? ~u : (u | 0x80000000u);
            unsigned long long key = ((unsigned long long)u << 32) | (unsigned)bc;
#pragma unroll
            for (int off = 1; off < 16; off <<= 1) {
                unsigned long long o = __shfl_xor(key, off, 64);
                if (o < key) key = o;
            }
            if (lrow == 0)
                atomicMin(&pm[n0 + wm * 64 + mi * 16 + lk * 4 + r], key);
        }
    }
}

// ---------------------------------------------------------------- epilogue
// grid (128, 2): x = 256-token chunk, y = d-half of 128
__global__ __launch_bounds__(256) void k_epi(const float* __restrict__ in,
                                             const float* __restrict__ E,
                                             const unsigned long long* __restrict__ pm,
                                             unsigned* __restrict__ counts,
                                             double* __restrict__ partials,
                                             float* __restrict__ out) {
    int n = blockIdx.x * 256 + threadIdx.x;
    int idx = (int)(pm[n] & 0xffffffffull);
    if (blockIdx.y == 0) atomicAdd(&counts[idx], 1u);

    int b = n >> 10, hw = n & 1023;
    size_t doff = (size_t)blockIdx.y * 128 * HWSZ;
    const float* zp = in + (size_t)b * BSTRIDE + hw + doff;
    float*       op = out + 1 + (size_t)b * BSTRIDE + hw + doff;   // out[0] = loss
    const float* ep = E + (size_t)idx * DDIM + blockIdx.y * 128;

    double s = 0.0;
#pragma unroll 4
    for (int d = 0; d < 128; ++d) {
        float ze = zp[(size_t)d * HWSZ];
        float zq = ep[d];
        float df = __fsub_rn(zq, ze);              // fl(zq - ze)
        float ov = __fadd_rn(ze, df);              // straight-through value
        op[(size_t)d * HWSZ] = ov;
        s += (double)__fmul_rn(df, df);
    }
    __shared__ double sd[256];
    sd[threadIdx.x] = s; __syncthreads();
    for (int off = 128; off; off >>= 1) {
        if (threadIdx.x < off) sd[threadIdx.x] += sd[threadIdx.x + off];
        __syncthreads();
    }
    if (threadIdx.x == 0) partials[blockIdx.x * 2 + blockIdx.y] = sd[0];
}

// ---------------------------------------------------------------- finalize
__global__ __launch_bounds__(256) void k_final(const double* __restrict__ partials,
                                               const unsigned* __restrict__ counts,
                                               float* __restrict__ out) {
    __shared__ double sd[256];
    int t = threadIdx.x;
    sd[t] = partials[t]; __syncthreads();
    for (int off = 128; off; off >>= 1) {
        if (t < off) sd[t] += sd[t + off];
        __syncthreads();
    }
    double msum = sd[0];
    __syncthreads();

    double es_ = 0.0;
#pragma unroll
    for (int j = 0; j < 4; ++j) {
        unsigned c = counts[t * 4 + j];
        float p = (float)c / 32768.0f;
        float term = __fmul_rn(p, log2f(__fadd_rn(p, 1e-10f)));
        es_ += (double)term;
    }
    sd[t] = es_; __syncthreads();
    for (int off = 128; off; off >>= 1) {
        if (t < off) sd[t] += sd[t + off];
        __syncthreads();
    }
    if (t == 0) {
        float e = (float)(msum / 8388608.0);       // mean over B*D*H*W
        float q = e;
        float loss = __fadd_rn(q, __fmul_rn(0.25f, e));
        float ent = -(float)sd[0];
        float words = exp2f(ent);
        out[0] = loss;
        out[1 + 8388608 + 0] = e;
        out[1 + 8388608 + 1] = q;
        out[1 + 8388608 + 2] = words;
    }
}

// ---------------------------------------------------------------- launch
extern "C" void kernel_launch(void* const* d_in, const int* in_sizes, int n_in,
                              void* d_out, int out_size, void* d_ws, size_t ws_size,
                              hipStream_t stream) {
    const float* in = (const float*)d_in[0];
    const float* E  = (const float*)d_in[1];
    float* out = (float*)d_out;
    char* ws = (char*)d_ws;
    float*              esq      = (float*)(ws + OFF_ESQ);
    unsigned short*     Ebf      = (unsigned short*)(ws + OFF_EBF);
    unsigned*           counts   = (unsigned*)(ws + OFF_CNT);
    double*             partials = (double*)(ws + OFF_PART);
    unsigned long long* pm       = (unsigned long long*)(ws + OFF_PM);

    hipLaunchKernelGGL(k_init, dim3(128), dim3(256), 0, stream, pm, counts);
    hipLaunchKernelGGL(k_prep, dim3(256), dim3(256), 0, stream, E, esq, Ebf);
    hipLaunchKernelGGL(k_gemm, dim3(2048), dim3(256), 0, stream, in, Ebf, esq, pm);
    hipLaunchKernelGGL(k_epi,  dim3(128, 2), dim3(256), 0, stream, in, E, pm, counts, partials, out);
    hipLaunchKernelGGL(k_final, dim3(1), dim3(256), 0, stream, partials, counts, out);
}